// Round 1
// baseline (126.184 us; speedup 1.0000x reference)
//
#include <hip/hip_runtime.h>
#include <math.h>

// Problem constants (match reference)
constexpr int B_ = 32;
constexpr int C_ = 32;
constexpr int RES_ = 16;
constexpr int G_ = RES_ * RES_ * RES_;   // 4096
constexpr int N_ = 16384;
constexpr int H_ = 64;
// sqrt(3)/RES
__device__ constexpr float REG_THR = 0.10825317547305483f;

// ---------------------------------------------------------------------------
// Kernel A: per-batch inclusive scan of counts (4096 cells) + direct expansion
// into idx[b][n] (the repeat_interleave index array). One block per batch.
// ---------------------------------------------------------------------------
__global__ __launch_bounds__(256) void expand_kernel(const int* __restrict__ counts,
                                                     int* __restrict__ idx_arr) {
    const int b = blockIdx.x;
    const int* cb = counts + b * G_;
    int* ib = idx_arr + b * N_;

    __shared__ int partials[256];
    const int t = threadIdx.x;
    const int base = t * 16;   // 256 threads * 16 cells = 4096

    int local[16];
    int s = 0;
#pragma unroll
    for (int i = 0; i < 16; ++i) {
        s += cb[base + i];
        local[i] = s;          // inclusive prefix within this thread's chunk
    }
    partials[t] = s;
    __syncthreads();

    // Hillis-Steele inclusive scan over the 256 partials
    for (int off = 1; off < 256; off <<= 1) {
        int v = (t >= off) ? partials[t - off] : 0;
        __syncthreads();
        partials[t] += v;
        __syncthreads();
    }
    const int prev = (t > 0) ? partials[t - 1] : 0;

    // cell (base+i) covers output slots [prev + local[i-1], prev + local[i])
#pragma unroll
    for (int i = 0; i < 16; ++i) {
        const int start = prev + (i > 0 ? local[i - 1] : 0);
        const int end   = prev + local[i];
        for (int j = start; j < end; ++j) ib[j] = base + i;
    }
}

// ---------------------------------------------------------------------------
// Kernel B: one thread per (b, n) point.
//   inp = [x[b, :, idx], b_rnd[b, :, n]]  (34 floats)
//   h = relu(W1 @ inp + b1); out = W2 @ h + b2
//   out0 = out + grid_o[:, idx];  reg = max(||out|| - sqrt(3)/RES, 0)
// Weights are read with wave-uniform addresses -> scalar loads (SGPR operands).
// ---------------------------------------------------------------------------
__global__ __launch_bounds__(256) void mlp_kernel(
    const float* __restrict__ x, const float* __restrict__ b_rnd,
    const float* __restrict__ grid_o, const float* __restrict__ W1,
    const float* __restrict__ b1, const float* __restrict__ W2,
    const float* __restrict__ b2, const int* __restrict__ idx_arr,
    float* __restrict__ out0, float* __restrict__ reg_out) {
    const int b = blockIdx.y;
    const int n = blockIdx.x * 256 + threadIdx.x;

    const int idx = idx_arr[b * N_ + n];

    float inp[34];
    const float* xb = x + ((size_t)b * C_) * G_ + idx;
#pragma unroll
    for (int c = 0; c < C_; ++c) inp[c] = xb[(size_t)c * G_];
    inp[32] = b_rnd[((size_t)b * 2 + 0) * N_ + n];
    inp[33] = b_rnd[((size_t)b * 2 + 1) * N_ + n];

    float o0 = b2[0], o1 = b2[1], o2 = b2[2];
#pragma unroll 4
    for (int h = 0; h < H_; ++h) {
        float acc = b1[h];
        const float* w = W1 + h * 34;
#pragma unroll
        for (int c = 0; c < 34; ++c) acc = fmaf(w[c], inp[c], acc);
        acc = fmaxf(acc, 0.0f);
        o0 = fmaf(W2[0 * H_ + h], acc, o0);
        o1 = fmaf(W2[1 * H_ + h], acc, o1);
        o2 = fmaf(W2[2 * H_ + h], acc, o2);
    }

    const float nrm = sqrtf(o0 * o0 + o1 * o1 + o2 * o2);
    const float reg = fmaxf(nrm - REG_THR, 0.0f);

    o0 += grid_o[0 * G_ + idx];
    o1 += grid_o[1 * G_ + idx];
    o2 += grid_o[2 * G_ + idx];

    float* p = out0 + ((size_t)b * 3) * N_ + n;
    p[0]              = o0;
    p[N_]             = o1;
    p[2 * (size_t)N_] = o2;
    reg_out[(size_t)b * N_ + n] = reg;
}

// ---------------------------------------------------------------------------
extern "C" void kernel_launch(void* const* d_in, const int* in_sizes, int n_in,
                              void* d_out, int out_size, void* d_ws, size_t ws_size,
                              hipStream_t stream) {
    const float* x      = (const float*)d_in[0];  // (B, C, RES, RES, RES)
    const int*   counts = (const int*)  d_in[1];  // (B, G)
    const float* b_rnd  = (const float*)d_in[2];  // (B, 2, N)
    const float* grid_o = (const float*)d_in[3];  // (3, G)
    const float* W1     = (const float*)d_in[4];  // (H, C+2)
    const float* b1     = (const float*)d_in[5];  // (H,)
    const float* W2     = (const float*)d_in[6];  // (3, H)
    const float* b2     = (const float*)d_in[7];  // (3,)

    float* out  = (float*)d_out;                      // (B, 3, N) then (B, N)
    float* rout = out + (size_t)B_ * 3 * N_;
    int*   idx_arr = (int*)d_ws;                      // B*N ints = 2 MB

    expand_kernel<<<B_, 256, 0, stream>>>(counts, idx_arr);

    dim3 grid(N_ / 256, B_);
    mlp_kernel<<<grid, 256, 0, stream>>>(x, b_rnd, grid_o, W1, b1, W2, b2,
                                         idx_arr, out, rout);
}

// Round 2
// 121.986 us; speedup vs baseline: 1.0344x; 1.0344x over previous
//
#include <hip/hip_runtime.h>
#include <math.h>

// Problem constants (match reference)
constexpr int B_ = 32;
constexpr int C_ = 32;
constexpr int RES_ = 16;
constexpr int G_ = RES_ * RES_ * RES_;   // 4096
constexpr int N_ = 16384;
constexpr int H_ = 64;
// sqrt(3)/RES
__device__ constexpr float REG_THR = 0.10825317547305483f;

// ---------------------------------------------------------------------------
// Kernel A: per-batch inclusive scan of counts (4096 cells) -> cum[b][G].
// One block per batch; tiny (~2-3 us). The expensive expansion is gone --
// the MLP kernel binary-searches cum directly.
// ---------------------------------------------------------------------------
__global__ __launch_bounds__(256) void scan_kernel(const int* __restrict__ counts,
                                                   int* __restrict__ cum) {
    const int b = blockIdx.x;
    const int* cb = counts + b * G_;
    int* ob = cum + b * G_;

    __shared__ int partials[256];
    const int t = threadIdx.x;
    const int base = t * 16;   // 256 threads * 16 cells = 4096

    int local[16];
    int s = 0;
#pragma unroll
    for (int i = 0; i < 16; ++i) {
        s += cb[base + i];
        local[i] = s;          // inclusive prefix within this thread's chunk
    }
    partials[t] = s;
    __syncthreads();

    // Hillis-Steele inclusive scan over the 256 partials
    for (int off = 1; off < 256; off <<= 1) {
        int v = (t >= off) ? partials[t - off] : 0;
        __syncthreads();
        partials[t] += v;
        __syncthreads();
    }
    const int prev = (t > 0) ? partials[t - 1] : 0;

#pragma unroll
    for (int i = 0; i < 16; ++i) ob[base + i] = prev + local[i];
}

// ---------------------------------------------------------------------------
// Kernel B: one thread per (b, n) point.
//   idx = searchsorted(cum[b], n, 'right')   (binary search in LDS copy)
//   inp = [x[b, :, idx], b_rnd[b, :, n]]     (34 floats, pinned to VGPRs)
//   h = relu(W1 @ inp + b1); out = W2 @ h + b2
//   out0 = out + grid_o[:, idx];  reg = max(||out|| - sqrt(3)/RES, 0)
// ---------------------------------------------------------------------------
__global__ __launch_bounds__(256) void mlp_kernel(
    const float* __restrict__ x, const float* __restrict__ b_rnd,
    const float* __restrict__ grid_o, const float* __restrict__ W1,
    const float* __restrict__ b1, const float* __restrict__ W2,
    const float* __restrict__ b2, const int* __restrict__ cum,
    float* __restrict__ out0, float* __restrict__ reg_out) {
    const int b = blockIdx.y;
    const int n = blockIdx.x * 256 + threadIdx.x;
    const int t = threadIdx.x;

    // Stage this batch's cumsum in LDS (16 KB), coalesced.
    __shared__ int s_cum[G_];
    const int* cb = cum + b * G_;
#pragma unroll
    for (int i = 0; i < G_ / 256; ++i) s_cum[t + i * 256] = cb[t + i * 256];
    __syncthreads();

    // searchsorted(cum, n, 'right'): smallest j with cum[j] > n
    int lo = 0, hi = G_ - 1;
#pragma unroll
    for (int it = 0; it < 12; ++it) {   // ceil(log2(4096)) = 12
        const int mid = (lo + hi) >> 1;
        if (s_cum[mid] > n) hi = mid; else lo = mid + 1;
        if (lo >= hi) { hi = lo; }
    }
    const int idx = lo;

    float inp[34];
    const float* xb = x + ((size_t)b * C_) * G_ + idx;
#pragma unroll
    for (int c = 0; c < C_; ++c) inp[c] = xb[(size_t)c * G_];
    inp[32] = b_rnd[((size_t)b * 2 + 0) * N_ + n];
    inp[33] = b_rnd[((size_t)b * 2 + 1) * N_ + n];

    // Pin inputs to VGPRs: the asm barrier makes each value opaque so the
    // compiler cannot rematerialize the global loads inside the h-loop
    // (round-1 kernel had VGPR_Count=28 -> it was re-reading x per h-chunk).
#pragma unroll
    for (int c = 0; c < 34; ++c) asm volatile("" : "+v"(inp[c]));

    float o0 = b2[0], o1 = b2[1], o2 = b2[2];
#pragma unroll 4
    for (int h = 0; h < H_; ++h) {
        float acc = b1[h];
        const float* w = W1 + h * 34;
#pragma unroll
        for (int c = 0; c < 34; ++c) acc = fmaf(w[c], inp[c], acc);
        acc = fmaxf(acc, 0.0f);
        o0 = fmaf(W2[0 * H_ + h], acc, o0);
        o1 = fmaf(W2[1 * H_ + h], acc, o1);
        o2 = fmaf(W2[2 * H_ + h], acc, o2);
    }

    const float nrm = sqrtf(o0 * o0 + o1 * o1 + o2 * o2);
    const float reg = fmaxf(nrm - REG_THR, 0.0f);

    o0 += grid_o[0 * G_ + idx];
    o1 += grid_o[1 * G_ + idx];
    o2 += grid_o[2 * G_ + idx];

    float* p = out0 + ((size_t)b * 3) * N_ + n;
    p[0]              = o0;
    p[N_]             = o1;
    p[2 * (size_t)N_] = o2;
    reg_out[(size_t)b * N_ + n] = reg;
}

// ---------------------------------------------------------------------------
extern "C" void kernel_launch(void* const* d_in, const int* in_sizes, int n_in,
                              void* d_out, int out_size, void* d_ws, size_t ws_size,
                              hipStream_t stream) {
    const float* x      = (const float*)d_in[0];  // (B, C, RES, RES, RES)
    const int*   counts = (const int*)  d_in[1];  // (B, G)
    const float* b_rnd  = (const float*)d_in[2];  // (B, 2, N)
    const float* grid_o = (const float*)d_in[3];  // (3, G)
    const float* W1     = (const float*)d_in[4];  // (H, C+2)
    const float* b1     = (const float*)d_in[5];  // (H,)
    const float* W2     = (const float*)d_in[6];  // (3, H)
    const float* b2     = (const float*)d_in[7];  // (3,)

    float* out  = (float*)d_out;                      // (B, 3, N) then (B, N)
    float* rout = out + (size_t)B_ * 3 * N_;
    int*   cum  = (int*)d_ws;                         // B*G ints = 512 KB

    scan_kernel<<<B_, 256, 0, stream>>>(counts, cum);

    dim3 grid(N_ / 256, B_);
    mlp_kernel<<<grid, 256, 0, stream>>>(x, b_rnd, grid_o, W1, b1, W2, b2,
                                         cum, out, rout);
}